// Round 1
// 194.554 us; speedup vs baseline: 1.0003x; 1.0003x over previous
//
#include <hip/hip_runtime.h>

#define T   512
#define B   512
#define NT  64
#define QS  16            // steps per staging quarter
#define NQ  (T / QS)      // 32 quarters
#define RING 4            // LDS ring: 4 quarters (64 steps), lead distance 3

typedef _Float16 h2 __attribute__((ext_vector_type(2)));

__device__ __forceinline__ float rflf(float x) {
    return __uint_as_float(__builtin_amdgcn_readfirstlane(__float_as_uint(x)));
}

__device__ __forceinline__ float dot2(h2 a, h2 b, float c) {
#if __has_builtin(__builtin_amdgcn_fdot2)
    return __builtin_amdgcn_fdot2(a, b, c, false);
#else
    return c + (float)a.x * (float)b.x + (float)a.y * (float)b.y;
#endif
}

// ---------------------------------------------------------------------------
// Fused CRF. Grid = 512 denom blocks (1 chain each, single wave) + 512
// numerator blocks.
//
// This round: same algorithm, restructured for the SGPR-forwarding hazard.
//   - broadcast phase-split: 8x v_readlane batched BEFORE the 8 dependent
//     v_dot2 (16-cycle separation beats the VALU-writes-SGPR hazard window;
//     previous code interleaved them at distance ~4 and stalled per pair),
//   - 8 accumulator chains (same-chain issue distance 16 cy),
//   - X values for each 4-step group ds_read at group top (explicit
//     prefetch, one lgkm wait per group fully covered by the matvec),
//   - mask select without touching VCC: wave-uniform bit -> scalar cselect
//     multiplier read as a plain SGPR operand, q = fma(mf, qn-q, q); the
//     all-ones quarter (the only case in this dataset) takes a uniform
//     branch with no select at all. K stays in an SGPR.
//   - qn = (p*X)*r so p*X overlaps the readfirstlane->SALU exponent path.
// ---------------------------------------------------------------------------
__global__ __launch_bounds__(64) void crf_fused(
    const float* __restrict__ emissions,  // [T, B, NT]
    const int*   __restrict__ tags,       // [T, B]
    const int*   __restrict__ mask,       // [T, B]
    const float* __restrict__ startT,     // [NT]
    const float* __restrict__ endT,       // [NT]
    const float* __restrict__ trans,      // [NT, NT]
    float* __restrict__ out)
{
    const int j = threadIdx.x;

    __shared__ __align__(16) float ebuf[RING][QS][NT];   // X = exp(e), 16 KB

    if (blockIdx.x < B) {
        // =============== denominator chain, b = blockIdx.x ==================
        const int b = blockIdx.x;

        // E = exp(trans) column j as f16 pairs over i (32 VGPRs)
        h2 Eh[NT / 2];
#pragma unroll
        for (int m = 0; m < NT / 2; ++m) {
            Eh[m].x = (_Float16)__expf(trans[(2 * m)     * NT + j]);
            Eh[m].y = (_Float16)__expf(trans[(2 * m + 1) * NT + j]);
        }

        // staging: lane j covers step 4k + (j>>4) of a quarter, cols (j&15)*4
        const int jr = j >> 4;
        const int c0 = (j & 15) * 4;
        float4 sA[4];

        auto issue_q = [&](int g) {
#pragma unroll
            for (int k = 0; k < 4; ++k) {
                const int t = g * QS + 4 * k + jr;
                sA[k] = *(const float4*)&emissions[((size_t)t * B + b) * NT + c0];
            }
        };
        auto write_q = [&](int g) {   // exp() applied here, off the chain
#pragma unroll
            for (int k = 0; k < 4; ++k) {
                float4 w;
                w.x = __expf(sA[k].x); w.y = __expf(sA[k].y);
                w.z = __expf(sA[k].z); w.w = __expf(sA[k].w);
                *(float4*)&ebuf[g & (RING - 1)][4 * k + jr][c0] = w;
            }
        };

        for (int g = 0; g < 3; ++g) { issue_q(g); write_q(g); }
        issue_q(3);

        // t = 0 init
        const float e0  = emissions[(size_t)b * NT + j];
        const float sc0 = startT[j] + e0;
        const float S0  = rflf(sc0);
        float q = __expf(sc0 - S0);
        int   K = 0;

        // initial f16 pair pack (even lane 2n holds (q_2n, q_2n+1))
        int pk_i;
        {
            const int qi = __float_as_int(q);
            const int qo = __builtin_amdgcn_update_dpp(0, qi, 0xB1, 0xF, 0xF, true);
            pk_i = __builtin_bit_cast(int,
                    __builtin_amdgcn_cvt_pkrtz(q, __int_as_float(qo)));
        }

        int mpre = mask[j * B + b];            // chunk-0 mask column
        unsigned long long mbc = 0;

        // matvec: p_j = sum_i q_i E[i][j], readlanes batched ahead of dots
        auto matvec_p = [&]() -> float {
            float a0 = 0.f, a1 = 0.f, a2 = 0.f, a3 = 0.f;
            float a4 = 0.f, a5 = 0.f, a6 = 0.f, a7 = 0.f;
#pragma unroll
            for (int h = 0; h < 4; ++h) {
                int u[8];
#pragma unroll
                for (int m = 0; m < 8; ++m)
                    u[m] = __builtin_amdgcn_readlane(pk_i, 16 * h + 2 * m);
                const int e = 8 * h;
                a0 = dot2(__builtin_bit_cast(h2, u[0]), Eh[e + 0], a0);
                a1 = dot2(__builtin_bit_cast(h2, u[1]), Eh[e + 1], a1);
                a2 = dot2(__builtin_bit_cast(h2, u[2]), Eh[e + 2], a2);
                a3 = dot2(__builtin_bit_cast(h2, u[3]), Eh[e + 3], a3);
                a4 = dot2(__builtin_bit_cast(h2, u[4]), Eh[e + 4], a4);
                a5 = dot2(__builtin_bit_cast(h2, u[5]), Eh[e + 5], a5);
                a6 = dot2(__builtin_bit_cast(h2, u[6]), Eh[e + 6], a6);
                a7 = dot2(__builtin_bit_cast(h2, u[7]), Eh[e + 7], a7);
            }
            return ((a0 + a1) + (a2 + a3)) + ((a4 + a5) + (a6 + a7));
        };

        auto repack = [&]() {
            const int qi = __float_as_int(q);
            const int qo = __builtin_amdgcn_update_dpp(0, qi, 0xB1, 0xF, 0xF, true);
            pk_i = __builtin_bit_cast(int,
                    __builtin_amdgcn_cvt_pkrtz(q, __int_as_float(qo)));
        };

        // power-of-2 renorm from lane-0 exponent (SALU side), no mask
        auto finish_fast = [&](float p, float X) {
            const int bits = __builtin_amdgcn_readfirstlane(__float_as_int(p));
            const int k    = ((bits >> 23) & 255) - 127;
            const float r  = __int_as_float((127 - k) << 23);
            const float pX = p * X;             // overlaps the SALU path
            q = pX * r;
            K += k;
            repack();
        };

        // masked variant: wave-uniform select, no VCC write on the chain
        auto finish_mask = [&](float p, float X, int ttc) {
            const int bits = __builtin_amdgcn_readfirstlane(__float_as_int(p));
            const int k    = ((bits >> 23) & 255) - 127;
            const float r  = __int_as_float((127 - k) << 23);
            const float pX = p * X;
            const float qn = pX * r;
            const bool mc  = (mbc >> ttc) & 1ull;
            const float mf = mc ? 1.0f : 0.0f;  // scalar cselect
            q = fmaf(mf, qn - q, q);            // mf=0 -> q exactly
            K += mc ? k : 0;
            repack();
        };

        for (int x = 0; x < NQ; ++x) {
            const int gw = (x + 3 < NQ) ? x + 3 : NQ - 1;
            write_q(gw);
            const int gl = (x + 4 < NQ) ? x + 4 : NQ - 1;
            issue_q(gl);

            if ((x & 3) == 0) {                // 64-step chunk boundary
                mbc = __ballot(mpre != 0);
                const int cn = ((x >> 2) + 1 < 8) ? (x >> 2) + 1 : 7;
                mpre = mask[(cn * 64 + j) * B + b];
            }

            const float* rowp = &ebuf[x & (RING - 1)][0][j];
            const unsigned qb = (unsigned)(mbc >> ((x & 3) << 4)) & 0xFFFFu;

            if (qb == 0xFFFFu) {
                // all 16 steps unmasked (the only case for this dataset)
#pragma unroll 1
                for (int gg = 0; gg < 4; ++gg) {
                    const float X0 = rowp[(4 * gg + 0) * NT];
                    const float X1 = rowp[(4 * gg + 1) * NT];
                    const float X2 = rowp[(4 * gg + 2) * NT];
                    const float X3 = rowp[(4 * gg + 3) * NT];
                    if (x + gg != 0) finish_fast(matvec_p(), X0); // skip t=0
                    finish_fast(matvec_p(), X1);
                    finish_fast(matvec_p(), X2);
                    finish_fast(matvec_p(), X3);
                }
            } else {
                const int base = (x & 3) << 4;
#pragma unroll 1
                for (int gg = 0; gg < 4; ++gg) {
                    const float X0 = rowp[(4 * gg + 0) * NT];
                    const float X1 = rowp[(4 * gg + 1) * NT];
                    const float X2 = rowp[(4 * gg + 2) * NT];
                    const float X3 = rowp[(4 * gg + 3) * NT];
                    const int t0 = base + 4 * gg;
                    if (x + gg != 0) finish_mask(matvec_p(), X0, t0);
                    finish_mask(matvec_p(), X1, t0 + 1);
                    finish_mask(matvec_p(), X2, t0 + 2);
                    finish_mask(matvec_p(), X3, t0 + 3);
                }
            }
        }

        // den_b = S0 + K*ln2 + log( sum_j q_j * exp(endT_j) )
        float v = q * __expf(endT[j]);
#pragma unroll
        for (int off = 32; off > 0; off >>= 1)
            v += __shfl_xor(v, off);
        if (j == 0)
            atomicAdd(out, -(S0 + (float)K * 0.69314718f + __logf(v)));

    } else {
        // =============== numerator wave, b = blockIdx.x - B =================
        const int b = blockIdx.x - B;

        float acc = 0.f;
        int   cnt = 0;
#pragma unroll
        for (int m = 0; m < T / 64; ++m) {
            const int t  = j + 64 * m;
            const int mv = mask[t * B + b];
            const int tg = tags[t * B + b];
            cnt += (int)__popcll(__ballot(mv != 0));
            if (t == 0) {
                acc += startT[tg] + emissions[(size_t)b * NT + tg];
            } else if (mv) {
                const int tp = tags[(t - 1) * B + b];
                acc += trans[tp * NT + tg]
                     + emissions[(size_t)(t * B + b) * NT + tg];
            }
        }
#pragma unroll
        for (int off = 32; off > 0; off >>= 1)
            acc += __shfl_xor(acc, off);
        if (j == 0) {
            const int last = tags[(size_t)(cnt - 1) * B + b];
            atomicAdd(out, acc + endT[last]);
        }
    }
}

extern "C" void kernel_launch(void* const* d_in, const int* in_sizes, int n_in,
                              void* d_out, int out_size, void* d_ws, size_t ws_size,
                              hipStream_t stream) {
    const float* emissions = (const float*)d_in[0];
    const int*   tags      = (const int*)  d_in[1];
    const int*   mask      = (const int*)  d_in[2];
    const float* startT    = (const float*)d_in[3];
    const float* endT      = (const float*)d_in[4];
    const float* trans     = (const float*)d_in[5];
    float* out = (float*)d_out;

    hipMemsetAsync(out, 0, sizeof(float), stream);
    crf_fused<<<2 * B, 64, 0, stream>>>(
        emissions, tags, mask, startT, endT, trans, out);
}

// Round 2
// 192.304 us; speedup vs baseline: 1.0120x; 1.0117x over previous
//
#include <hip/hip_runtime.h>

#define T   512
#define B   512
#define NT  64
#define QS  16            // steps per staging quarter
#define NQ  (T / QS)      // 32 quarters
#define RING 4            // LDS ring: 4 quarters (64 steps), lead distance 3

typedef _Float16 h2 __attribute__((ext_vector_type(2)));

__device__ __forceinline__ float rflf(float x) {
    return __uint_as_float(__builtin_amdgcn_readfirstlane(__float_as_uint(x)));
}

__device__ __forceinline__ float dot2(h2 a, h2 b, float c) {
#if __has_builtin(__builtin_amdgcn_fdot2)
    return __builtin_amdgcn_fdot2(a, b, c, false);
#else
    return c + (float)a.x * (float)b.x + (float)a.y * (float)b.y;
#endif
}

__device__ __forceinline__ h2 bch2(int u) { return __builtin_bit_cast(h2, u); }

// ---------------------------------------------------------------------------
// Fused CRF. Grid = 512 denom blocks (1 chain each, single wave) + 512
// numerator blocks.
//
// Round 2: rounds 0/1 proved the stall is NOT a short SGPR hazard (identical
// time at readlane->dot distance 4 and 16). Remaining candidates are the
// 32x v_readlane broadcast itself, I-fetch of the ~20KB unrolled body, and
// ds_read placement. This round removes all three:
//   - q broadcast via LDS: all lanes write pk_i (even lanes -> qlds[0..31],
//     odd lanes -> dump 32..63; 2 lanes/bank = free), then 8x ds_read_b128
//     at a wave-uniform address (broadcast, conflict-free). Bit-identical
//     pair words and dot order vs the readlane version.
//   - step loop ROLLED (#pragma unroll 1): body ~400B, I$-resident.
//   - X prefetched one full step ahead (loop-carried ds_read).
// Renorm stays power-of-2 from lane-0 exponent bits; score = S0 + K*ln2
// + log q. No exp/log/rcp and no global access on the serial chain.
// ---------------------------------------------------------------------------
__global__ __launch_bounds__(64) void crf_fused(
    const float* __restrict__ emissions,  // [T, B, NT]
    const int*   __restrict__ tags,       // [T, B]
    const int*   __restrict__ mask,       // [T, B]
    const float* __restrict__ startT,     // [NT]
    const float* __restrict__ endT,       // [NT]
    const float* __restrict__ trans,      // [NT, NT]
    float* __restrict__ out)
{
    const int j = threadIdx.x;

    __shared__ __align__(16) float ebuf[RING][QS][NT];   // X = exp(e), 16 KB
    __shared__ __align__(16) int   qlds[64];             // pk pairs + dump

    if (blockIdx.x < B) {
        // =============== denominator chain, b = blockIdx.x ==================
        const int b = blockIdx.x;

        // E = exp(trans) column j as f16 pairs over i (32 VGPRs)
        h2 Eh[NT / 2];
#pragma unroll
        for (int m = 0; m < NT / 2; ++m) {
            Eh[m].x = (_Float16)__expf(trans[(2 * m)     * NT + j]);
            Eh[m].y = (_Float16)__expf(trans[(2 * m + 1) * NT + j]);
        }

        // staging: lane j covers step 4k + (j>>4) of a quarter, cols (j&15)*4
        const int jr = j >> 4;
        const int c0 = (j & 15) * 4;
        float4 sA[4];

        auto issue_q = [&](int g) {
#pragma unroll
            for (int k = 0; k < 4; ++k) {
                const int t = g * QS + 4 * k + jr;
                sA[k] = *(const float4*)&emissions[((size_t)t * B + b) * NT + c0];
            }
        };
        auto write_q = [&](int g) {   // exp() applied here, off the chain
#pragma unroll
            for (int k = 0; k < 4; ++k) {
                float4 w;
                w.x = __expf(sA[k].x); w.y = __expf(sA[k].y);
                w.z = __expf(sA[k].z); w.w = __expf(sA[k].w);
                *(float4*)&ebuf[g & (RING - 1)][4 * k + jr][c0] = w;
            }
        };

        for (int g = 0; g < 3; ++g) { issue_q(g); write_q(g); }
        issue_q(3);

        // t = 0 init
        const float e0  = emissions[(size_t)b * NT + j];
        const float sc0 = startT[j] + e0;
        const float S0  = rflf(sc0);
        float q = __expf(sc0 - S0);
        int   K = 0;

        // initial f16 pair pack (even lane 2n holds (q_2n, q_2n+1))
        int pk_i;
        {
            const int qi = __float_as_int(q);
            const int qo = __builtin_amdgcn_update_dpp(0, qi, 0xB1, 0xF, 0xF, true);
            pk_i = __builtin_bit_cast(int,
                    __builtin_amdgcn_cvt_pkrtz(q, __int_as_float(qo)));
        }

        // broadcast slot: even lane 2n -> word n, odd lanes -> dump 32..63
        const int qslot = (j & 1) ? (32 + (j >> 1)) : (j >> 1);

        int mpre = mask[j * B + b];            // chunk-0 mask column
        unsigned long long mbc = 0;

        // matvec via LDS broadcast: p_j = sum_i q_i E[i][j]
        auto matvec_b = [&]() -> float {
            qlds[qslot] = pk_i;                       // ds_write_b32
            const int4* qw = (const int4*)qlds;
            int4 w[8];
#pragma unroll
            for (int m = 0; m < 8; ++m) w[m] = qw[m]; // 8x ds_read_b128 bcast
            float a0 = 0.f, a1 = 0.f, a2 = 0.f, a3 = 0.f;
            float a4 = 0.f, a5 = 0.f, a6 = 0.f, a7 = 0.f;
#pragma unroll
            for (int h = 0; h < 4; ++h) {
                const int4 wa = w[2 * h];
                const int4 wb = w[2 * h + 1];
                const int e = 8 * h;
                a0 = dot2(bch2(wa.x), Eh[e + 0], a0);
                a1 = dot2(bch2(wa.y), Eh[e + 1], a1);
                a2 = dot2(bch2(wa.z), Eh[e + 2], a2);
                a3 = dot2(bch2(wa.w), Eh[e + 3], a3);
                a4 = dot2(bch2(wb.x), Eh[e + 4], a4);
                a5 = dot2(bch2(wb.y), Eh[e + 5], a5);
                a6 = dot2(bch2(wb.z), Eh[e + 6], a6);
                a7 = dot2(bch2(wb.w), Eh[e + 7], a7);
            }
            return ((a0 + a1) + (a2 + a3)) + ((a4 + a5) + (a6 + a7));
        };

        auto repack = [&]() {
            const int qi = __float_as_int(q);
            const int qo = __builtin_amdgcn_update_dpp(0, qi, 0xB1, 0xF, 0xF, true);
            pk_i = __builtin_bit_cast(int,
                    __builtin_amdgcn_cvt_pkrtz(q, __int_as_float(qo)));
        };

        // power-of-2 renorm from lane-0 exponent (SALU side), no mask
        auto finish_fast = [&](float p, float X) {
            const int bits = __builtin_amdgcn_readfirstlane(__float_as_int(p));
            const int k    = ((bits >> 23) & 255) - 127;
            const float r  = __int_as_float((127 - k) << 23);
            const float pX = p * X;             // overlaps the SALU path
            q = pX * r;
            K += k;
            repack();
        };

        // masked variant: wave-uniform select, no VCC write on the chain
        auto finish_mask = [&](float p, float X, int ttc) {
            const int bits = __builtin_amdgcn_readfirstlane(__float_as_int(p));
            const int k    = ((bits >> 23) & 255) - 127;
            const float r  = __int_as_float((127 - k) << 23);
            const float pX = p * X;
            const float qn = pX * r;
            const bool mc  = (mbc >> ttc) & 1ull;
            const float mf = mc ? 1.0f : 0.0f;  // scalar cselect
            q = fmaf(mf, qn - q, q);            // mf=0 -> q exactly
            K += mc ? k : 0;
            repack();
        };

        for (int x = 0; x < NQ; ++x) {
            const int gw = (x + 3 < NQ) ? x + 3 : NQ - 1;
            write_q(gw);
            const int gl = (x + 4 < NQ) ? x + 4 : NQ - 1;
            issue_q(gl);

            if ((x & 3) == 0) {                // 64-step chunk boundary
                mbc = __ballot(mpre != 0);
                const int cn = ((x >> 2) + 1 < 8) ? (x >> 2) + 1 : 7;
                mpre = mask[(cn * 64 + j) * B + b];
            }

            const float* rowp = &ebuf[x & (RING - 1)][0][j];
            const unsigned qb = (unsigned)(mbc >> ((x & 3) << 4)) & 0xFFFFu;
            const int t0 = (x == 0) ? 1 : 0;
            float Xc = rowp[t0 * NT];          // X for first step of quarter

            if (qb == 0xFFFFu) {
                // all 16 steps unmasked (the only case for this dataset)
#pragma unroll 1
                for (int tt = t0; tt < QS; ++tt) {
                    const int tn = (tt + 1 < QS) ? tt + 1 : QS - 1;
                    const float p  = matvec_b();
                    const float Xn = rowp[tn * NT];   // next step's X
                    finish_fast(p, Xc);
                    Xc = Xn;
                }
            } else {
                const int base = (x & 3) << 4;
#pragma unroll 1
                for (int tt = t0; tt < QS; ++tt) {
                    const int tn = (tt + 1 < QS) ? tt + 1 : QS - 1;
                    const float p  = matvec_b();
                    const float Xn = rowp[tn * NT];
                    finish_mask(p, Xc, base + tt);
                    Xc = Xn;
                }
            }
        }

        // den_b = S0 + K*ln2 + log( sum_j q_j * exp(endT_j) )
        float v = q * __expf(endT[j]);
#pragma unroll
        for (int off = 32; off > 0; off >>= 1)
            v += __shfl_xor(v, off);
        if (j == 0)
            atomicAdd(out, -(S0 + (float)K * 0.69314718f + __logf(v)));

    } else {
        // =============== numerator wave, b = blockIdx.x - B =================
        const int b = blockIdx.x - B;

        float acc = 0.f;
        int   cnt = 0;
#pragma unroll
        for (int m = 0; m < T / 64; ++m) {
            const int t  = j + 64 * m;
            const int mv = mask[t * B + b];
            const int tg = tags[t * B + b];
            cnt += (int)__popcll(__ballot(mv != 0));
            if (t == 0) {
                acc += startT[tg] + emissions[(size_t)b * NT + tg];
            } else if (mv) {
                const int tp = tags[(t - 1) * B + b];
                acc += trans[tp * NT + tg]
                     + emissions[(size_t)(t * B + b) * NT + tg];
            }
        }
#pragma unroll
        for (int off = 32; off > 0; off >>= 1)
            acc += __shfl_xor(acc, off);
        if (j == 0) {
            const int last = tags[(size_t)(cnt - 1) * B + b];
            atomicAdd(out, acc + endT[last]);
        }
    }
}

extern "C" void kernel_launch(void* const* d_in, const int* in_sizes, int n_in,
                              void* d_out, int out_size, void* d_ws, size_t ws_size,
                              hipStream_t stream) {
    const float* emissions = (const float*)d_in[0];
    const int*   tags      = (const int*)  d_in[1];
    const int*   mask      = (const int*)  d_in[2];
    const float* startT    = (const float*)d_in[3];
    const float* endT      = (const float*)d_in[4];
    const float* trans     = (const float*)d_in[5];
    float* out = (float*)d_out;

    hipMemsetAsync(out, 0, sizeof(float), stream);
    crf_fused<<<2 * B, 64, 0, stream>>>(
        emissions, tags, mask, startT, endT, trans, out);
}